// Round 9
// baseline (228.483 us; speedup 1.0000x reference)
//
#include <hip/hip_runtime.h>
#include <math.h>

// B=16, N=1024, C_IN=256, C_OUT=256, POOL_RATIO=0.5
#define Bsz 16
#define Nn  1024

// d_out layout (float32): x_out[16,1024,256], adj_out[16,1024,1024], new_mask[16,1024], new_n[16]
#define ADJ_OFF    (16*1024*256)
#define MASK_OFF   (ADJ_OFF + 16*1024*1024)
#define NN_OFF     (MASK_OFF + 16*1024)

typedef unsigned long long u64;
typedef unsigned short u16;
typedef short bf16x8 __attribute__((ext_vector_type(8)));
typedef float f32x4  __attribute__((ext_vector_type(4)));

static __device__ inline u16 f2bf(float f) {
    unsigned u = __float_as_uint(f);
    u += 0x7fffu + ((u >> 16) & 1u);
    return (u16)(u >> 16);
}

// =============== k1: x->bf16 + z = x.(W.pool) (blocks 0-255) | W^T bf16 (blocks 256-271) ===============
__global__ __launch_bounds__(256) void k1(const float* __restrict__ x,
                                          const float* __restrict__ W,
                                          const float* __restrict__ pool,
                                          u16* __restrict__ XB,
                                          u16* __restrict__ WT,
                                          float* __restrict__ Z) {
    int bid = blockIdx.x, t = threadIdx.x, lane = t & 63, wid = t >> 6;
    if (bid < 256) {
        __shared__ float sp[256];
        __shared__ float swp[256];
        sp[t] = pool[t];
        __syncthreads();
        float acc = 0.f;
        const float* wr = W + t * 256;
        for (int j = 0; j < 256; j += 4) {
            float4 w4 = *(const float4*)&wr[j];
            acc = fmaf(w4.x, sp[j], fmaf(w4.y, sp[j + 1],
                  fmaf(w4.z, sp[j + 2], fmaf(w4.w, sp[j + 3], acc))));
        }
        swp[t] = acc;
        __syncthreads();
        const float* w4p = &swp[lane * 4];
        float wx = w4p[0], wy = w4p[1], wz = w4p[2], ww = w4p[3];
        int base = bid * 64 + wid * 16;
        #pragma unroll 1
        for (int rb = 0; rb < 4; ++rb) {
            float4 v[4];
            #pragma unroll
            for (int k = 0; k < 4; ++k)
                v[k] = ((const float4*)(x + (size_t)(base + rb * 4 + k) * 256))[lane];
            #pragma unroll
            for (int k = 0; k < 4; ++k) {
                int row = base + rb * 4 + k;
                ushort4 o;
                o.x = f2bf(v[k].x); o.y = f2bf(v[k].y); o.z = f2bf(v[k].z); o.w = f2bf(v[k].w);
                ((ushort4*)(XB + (size_t)row * 256))[lane] = o;
                float a = fmaf(v[k].x, wx, fmaf(v[k].y, wy, fmaf(v[k].z, wz, v[k].w * ww)));
                for (int off = 32; off > 0; off >>= 1) a += __shfl_down(a, off, 64);
                if (lane == 0) Z[row] = a;
            }
        }
    } else {
        __shared__ float sT[64][65];
        int bt = bid - 256;
        int tr = (bt >> 2) * 64, tc = (bt & 3) * 64;
        #pragma unroll
        for (int p = 0; p < 4; ++p) {
            int r = p * 16 + (t >> 4), c = (t & 15) * 4;
            float4 w = *(const float4*)&W[(size_t)(tr + r) * 256 + tc + c];
            sT[r][c] = w.x; sT[r][c + 1] = w.y; sT[r][c + 2] = w.z; sT[r][c + 3] = w.w;
        }
        __syncthreads();
        #pragma unroll
        for (int p = 0; p < 2; ++p) {
            int nl = p * 32 + (t >> 3), kl = (t & 7) * 8;
            u16 tmp[8];
            #pragma unroll
            for (int j = 0; j < 8; ++j) tmp[j] = f2bf(sT[kl + j][nl]);
            *(int4*)&WT[(size_t)(tc + nl) * 256 + tr + kl] = *(const int4*)tmp;
        }
    }
}

// =============== k2: XWBT = (XB@WT^T)^T per batch (blocks 0-255) | adj->AB bf16 + y (blocks 256-1279) ===============
__global__ __launch_bounds__(256) void k2(const u16* __restrict__ XB,
                                          const u16* __restrict__ WT,
                                          const float* __restrict__ adj,
                                          const float* __restrict__ Z,
                                          u16* __restrict__ XWBT,
                                          u16* __restrict__ AB,
                                          float* __restrict__ Y) {
    int t = threadIdx.x, lane = t & 63, wid = t >> 6;
    if (blockIdx.x < 256) {
        __shared__ short sA[128][72];
        __shared__ short sB[128][72];
        int bm = blockIdx.x >> 1, bn = blockIdx.x & 1;
        int wr = (wid >> 1) * 64, wc = (wid & 1) * 64;
        int fm = lane & 15, fq = lane >> 4;

        f32x4 acc[4][4];
        #pragma unroll
        for (int i = 0; i < 4; ++i)
            #pragma unroll
            for (int j = 0; j < 4; ++j)
                acc[i][j] = (f32x4){0.f, 0.f, 0.f, 0.f};

        int sr = t >> 1, half = (t & 1) * 32;
        const u16* gA = XB + ((size_t)(bm * 128 + sr)) * 256 + half;
        const u16* gB = WT + ((size_t)(bn * 128 + sr)) * 256 + half;

        for (int kt = 0; kt < 4; ++kt) {
            __syncthreads();
            #pragma unroll
            for (int q = 0; q < 4; ++q) {
                *(int4*)&sA[sr][half + q * 8] = *(const int4*)&gA[kt * 64 + q * 8];
                *(int4*)&sB[sr][half + q * 8] = *(const int4*)&gB[kt * 64 + q * 8];
            }
            __syncthreads();
            #pragma unroll
            for (int ks = 0; ks < 64; ks += 32) {
                bf16x8 af[4], bfv[4];
                #pragma unroll
                for (int i = 0; i < 4; ++i)
                    af[i] = *(const bf16x8*)&sA[wr + i * 16 + fm][ks + fq * 8];
                #pragma unroll
                for (int j = 0; j < 4; ++j)
                    bfv[j] = *(const bf16x8*)&sB[wc + j * 16 + fm][ks + fq * 8];
                #pragma unroll
                for (int i = 0; i < 4; ++i)
                    #pragma unroll
                    for (int j = 0; j < 4; ++j)
                        acc[i][j] = __builtin_amdgcn_mfma_f32_16x16x32_bf16(af[i], bfv[j], acc[i][j], 0, 0, 0);
            }
        }
        // write transposed: XWBT[b][n][m_local], m contiguous
        int b = bm >> 3;
        #pragma unroll
        for (int i = 0; i < 4; ++i) {
            int rloc = (bm & 7) * 128 + wr + i * 16 + fq * 4;
            #pragma unroll
            for (int j = 0; j < 4; ++j) {
                int c = bn * 128 + wc + j * 16 + fm;
                u16 tmp[4];
                #pragma unroll
                for (int r = 0; r < 4; ++r) tmp[r] = f2bf(acc[i][j][r]);
                *(unsigned long long*)&XWBT[(size_t)b * 262144 + (size_t)c * 1024 + rloc] =
                    *(const unsigned long long*)tmp;
            }
        }
    } else {
        int g = blockIdx.x - 256;
        int b = g >> 6, grp = g & 63;
        __shared__ float sZ[1024];
        ((float4*)sZ)[t] = ((const float4*)(Z + (b << 10)))[t];
        __syncthreads();
        const float* z0 = &sZ[lane * 4];
        #pragma unroll 1
        for (int rr = 0; rr < 4; ++rr) {
            int row = (b << 10) + grp * 16 + wid * 4 + rr;
            const float4* ar = (const float4*)(adj + (size_t)row * 1024);
            float4 v0 = ar[lane], v1 = ar[64 + lane], v2 = ar[128 + lane], v3 = ar[192 + lane];
            u16* abr = AB + (size_t)row * 1024;
            ushort4 o0, o1, o2, o3;
            o0.x = f2bf(v0.x); o0.y = f2bf(v0.y); o0.z = f2bf(v0.z); o0.w = f2bf(v0.w);
            o1.x = f2bf(v1.x); o1.y = f2bf(v1.y); o1.z = f2bf(v1.z); o1.w = f2bf(v1.w);
            o2.x = f2bf(v2.x); o2.y = f2bf(v2.y); o2.z = f2bf(v2.z); o2.w = f2bf(v2.w);
            o3.x = f2bf(v3.x); o3.y = f2bf(v3.y); o3.z = f2bf(v3.z); o3.w = f2bf(v3.w);
            ((ushort4*)abr)[lane] = o0;
            ((ushort4*)abr)[64 + lane] = o1;
            ((ushort4*)abr)[128 + lane] = o2;
            ((ushort4*)abr)[192 + lane] = o3;
            float a = v0.x * z0[0] + v0.y * z0[1] + v0.z * z0[2] + v0.w * z0[3];
            a += v1.x * z0[256] + v1.y * z0[257] + v1.z * z0[258] + v1.w * z0[259];
            a += v2.x * z0[512] + v2.y * z0[513] + v2.z * z0[514] + v2.w * z0[515];
            a += v3.x * z0[768] + v3.y * z0[769] + v3.z * z0[770] + v3.w * z0[771];
            for (int off = 32; off > 0; off >>= 1) a += __shfl_down(a, off, 64);
            if (lane == 0) Y[row] = a;
        }
    }
}

// =============== k3: rank-count mask (no sort) + scale + bitmap ===============
// remove_i <=> mask_i && #{masked j: (y_j,j) < (y_i,i)} < n_remove  == reference sorted-rank semantics
__global__ __launch_bounds__(256) void k3(const float* __restrict__ Y,
                                          const int* __restrict__ maskIn,
                                          const int* __restrict__ nNodes,
                                          const float* __restrict__ bias,
                                          const float* __restrict__ pool,
                                          float* __restrict__ SCALE,
                                          float* __restrict__ NM,
                                          float* __restrict__ newN,
                                          u64* __restrict__ NMBITS) {
    __shared__ float sy[1024];
    __shared__ int   sm[1024];
    __shared__ float redb[4], redq[4];
    __shared__ float sBP, sINV;
    int b = blockIdx.x >> 2, part = blockIdx.x & 3;
    int t = threadIdx.x, lane = t & 63, wid = t >> 6;
    int base = b << 10;

    for (int j = t; j < 1024; j += 256) {
        sy[j] = Y[base + j];
        sm[j] = maskIn[base + j];
    }
    {
        float pv = pool[t];
        float bv = bias[t] * pv;
        float qv = pv * pv;
        for (int off = 32; off > 0; off >>= 1) {
            bv += __shfl_down(bv, off, 64);
            qv += __shfl_down(qv, off, 64);
        }
        if (lane == 0) { redb[wid] = bv; redq[wid] = qv; }
    }
    __syncthreads();
    if (t == 0) {
        sBP  = redb[0] + redb[1] + redb[2] + redb[3];
        sINV = 1.0f / sqrtf(redq[0] + redq[1] + redq[2] + redq[3]);
    }
    __syncthreads();

    int i = part * 256 + t;
    float yi = sy[i];
    int cnt = 0;
    #pragma unroll 4
    for (int j = 0; j < 1024; ++j) {
        float yj = sy[j];
        bool less = (yj < yi) || (yj == yi && j < i);
        cnt += less ? sm[j] : 0;
    }
    int nn = nNodes[b];
    int nrem = (int)((float)nn * 0.5f);
    int mi = sm[i];
    int nm = (mi == 1 && cnt < nrem) ? 0 : mi;
    NM[base + i] = (float)nm;
    SCALE[base + i] = nm ? tanhf((yi + sBP) * sINV) : 0.0f;
    u64 bm = __ballot(nm != 0);
    if (lane == 0) NMBITS[b * 16 + part * 4 + wid] = bm;
    if (t == 0 && part == 0) newN[b] = (float)(nn - nrem);
}

// =============== k4: H=AB@XWBT^T + x_out epilogue (blocks 0-255) | AO dense write (blocks 256-1279) ===============
__global__ __launch_bounds__(256) void k4(const u16* __restrict__ AB,
                                          const u16* __restrict__ XWBT,
                                          const float* __restrict__ SCALE,
                                          const float* __restrict__ bias,
                                          const u64* __restrict__ NMBITS,
                                          float* __restrict__ XO,
                                          float* __restrict__ AO) {
    int t = threadIdx.x, lane = t & 63, wid = t >> 6;
    if (blockIdx.x < 256) {
        __shared__ short sA[128][72];
        __shared__ short sB[128][72];
        int idx = blockIdx.x;
        int bn = idx & 1, bmt = (idx >> 1) & 7, b = idx >> 4;
        int wr = (wid >> 1) * 64, wc = (wid & 1) * 64;
        int fm = lane & 15, fq = lane >> 4;

        f32x4 acc[4][4];
        #pragma unroll
        for (int i = 0; i < 4; ++i)
            #pragma unroll
            for (int j = 0; j < 4; ++j)
                acc[i][j] = (f32x4){0.f, 0.f, 0.f, 0.f};

        int sr = t >> 1, half = (t & 1) * 32;
        const u16* gA = AB + ((size_t)(b * 1024 + bmt * 128 + sr)) * 1024 + half;
        const u16* gB = XWBT + (size_t)b * 262144 + (size_t)(bn * 128 + sr) * 1024 + half;

        for (int kt = 0; kt < 16; ++kt) {
            __syncthreads();
            #pragma unroll
            for (int q = 0; q < 4; ++q) {
                *(int4*)&sA[sr][half + q * 8] = *(const int4*)&gA[kt * 64 + q * 8];
                *(int4*)&sB[sr][half + q * 8] = *(const int4*)&gB[kt * 64 + q * 8];
            }
            __syncthreads();
            #pragma unroll
            for (int ks = 0; ks < 64; ks += 32) {
                bf16x8 af[4], bfv[4];
                #pragma unroll
                for (int i = 0; i < 4; ++i)
                    af[i] = *(const bf16x8*)&sA[wr + i * 16 + fm][ks + fq * 8];
                #pragma unroll
                for (int j = 0; j < 4; ++j)
                    bfv[j] = *(const bf16x8*)&sB[wc + j * 16 + fm][ks + fq * 8];
                #pragma unroll
                for (int i = 0; i < 4; ++i)
                    #pragma unroll
                    for (int j = 0; j < 4; ++j)
                        acc[i][j] = __builtin_amdgcn_mfma_f32_16x16x32_bf16(af[i], bfv[j], acc[i][j], 0, 0, 0);
            }
        }
        float bj[4];
        #pragma unroll
        for (int j = 0; j < 4; ++j) bj[j] = bias[bn * 128 + wc + j * 16 + fm];
        int mb = (b << 10) + bmt * 128 + wr;
        #pragma unroll
        for (int i = 0; i < 4; ++i) {
            int m0 = mb + i * 16 + fq * 4;
            float s0 = SCALE[m0], s1 = SCALE[m0 + 1], s2 = SCALE[m0 + 2], s3 = SCALE[m0 + 3];
            #pragma unroll
            for (int j = 0; j < 4; ++j) {
                int c = bn * 128 + wc + j * 16 + fm;
                float* xo = XO + (size_t)m0 * 256 + c;
                xo[0]   = (acc[i][j][0] + bj[j]) * s0;
                xo[256] = (acc[i][j][1] + bj[j]) * s1;
                xo[512] = (acc[i][j][2] + bj[j]) * s2;
                xo[768] = (acc[i][j][3] + bj[j]) * s3;
            }
        }
    } else {
        int g = blockIdx.x - 256;
        int b = g >> 6, grp = g & 63;
        __shared__ u64 sBits[16];
        if (t < 16) sBits[t] = NMBITS[b * 16 + t];
        __syncthreads();
        int c0 = t * 4;
        u64 wb = sBits[c0 >> 6] >> (c0 & 63);
        float m0 = (wb & 1) ? 1.f : 0.f;
        float m1 = ((wb >> 1) & 1) ? 1.f : 0.f;
        float m2 = ((wb >> 2) & 1) ? 1.f : 0.f;
        float m3 = ((wb >> 3) & 1) ? 1.f : 0.f;
        #pragma unroll 1
        for (int r = 0; r < 16; ++r) {
            int rloc = grp * 16 + r;
            int nmRow = (int)((sBits[rloc >> 6] >> (rloc & 63)) & 1ULL);
            float4* aor = (float4*)(AO + (size_t)((b << 10) + rloc) * 1024);
            if (nmRow) {
                ushort4 ab = ((const ushort4*)(AB + (size_t)((b << 10) + rloc) * 1024))[t];
                float4 o;
                o.x = ab.x ? m0 : 0.f;
                o.y = ab.y ? m1 : 0.f;
                o.z = ab.z ? m2 : 0.f;
                o.w = ab.w ? m3 : 0.f;
                aor[t] = o;
            } else {
                aor[t] = make_float4(0.f, 0.f, 0.f, 0.f);
            }
        }
    }
}

extern "C" void kernel_launch(void* const* d_in, const int* in_sizes, int n_in,
                              void* d_out, int out_size, void* d_ws, size_t ws_size,
                              hipStream_t stream) {
    const float* x      = (const float*)d_in[0];
    const float* adj    = (const float*)d_in[1];
    const int*   mask   = (const int*)d_in[2];
    const int*   nnodes = (const int*)d_in[3];
    const float* W      = (const float*)d_in[4];
    const float* bias   = (const float*)d_in[5];
    const float* pool   = (const float*)d_in[6];

    float* out = (float*)d_out;
    float* XO  = out;
    float* AO  = out + ADJ_OFF;
    float* NM  = out + MASK_OFF;
    float* NNo = out + NN_OFF;

    char* w = (char*)d_ws;
    u16*   XB     = (u16*)(w);                    //  8,388,608 B
    u16*   WT     = (u16*)(w + 8388608);          //    131,072
    u16*   XWBT   = (u16*)(w + 8519680);          //  8,388,608
    u16*   AB     = (u16*)(w + 16908288);         // 33,554,432
    float* Z      = (float*)(w + 50462720);       //     65,536
    float* Y      = (float*)(w + 50528256);       //     65,536
    float* SCALE  = (float*)(w + 50593792);       //     65,536
    u64*   NMBITS = (u64*)(w + 50659328);         //      2,048

    k1<<<272, 256, 0, stream>>>(x, W, pool, XB, WT, Z);
    k2<<<1280, 256, 0, stream>>>(XB, WT, adj, Z, XWBT, AB, Y);
    k3<<<Bsz * 4, 256, 0, stream>>>(Y, mask, nnodes, bias, pool, SCALE, NM, NNo, NMBITS);
    k4<<<1280, 256, 0, stream>>>(AB, XWBT, SCALE, bias, NMBITS, XO, AO);
}

// Round 10
// 206.504 us; speedup vs baseline: 1.1064x; 1.1064x over previous
//
#include <hip/hip_runtime.h>
#include <math.h>

// B=16, N=1024, C_IN=256, C_OUT=256, POOL_RATIO=0.5
#define Bsz 16
#define Nn  1024

// d_out layout (float32): x_out[16,1024,256], adj_out[16,1024,1024], new_mask[16,1024], new_n[16]
#define ADJ_OFF    (16*1024*256)
#define MASK_OFF   (ADJ_OFF + 16*1024*1024)
#define NN_OFF     (MASK_OFF + 16*1024)

typedef unsigned long long u64;
typedef unsigned short u16;
typedef short bf16x8 __attribute__((ext_vector_type(8)));
typedef float f32x4  __attribute__((ext_vector_type(4)));

static __device__ inline u16 f2bf(float f) {
    unsigned u = __float_as_uint(f);
    u += 0x7fffu + ((u >> 16) & 1u);
    return (u16)(u >> 16);
}

// =============== k1: x->bf16 + z = x.(W.pool) (blocks 0-255) | W^T bf16 (blocks 256-271) ===============
__global__ __launch_bounds__(256) void k1(const float* __restrict__ x,
                                          const float* __restrict__ W,
                                          const float* __restrict__ pool,
                                          u16* __restrict__ XB,
                                          u16* __restrict__ WT,
                                          float* __restrict__ Z) {
    int bid = blockIdx.x, t = threadIdx.x, lane = t & 63, wid = t >> 6;
    if (bid < 256) {
        __shared__ float sp[256];
        __shared__ float swp[256];
        sp[t] = pool[t];
        __syncthreads();
        float acc = 0.f;
        const float* wr = W + t * 256;
        for (int j = 0; j < 256; j += 4) {
            float4 w4 = *(const float4*)&wr[j];
            acc = fmaf(w4.x, sp[j], fmaf(w4.y, sp[j + 1],
                  fmaf(w4.z, sp[j + 2], fmaf(w4.w, sp[j + 3], acc))));
        }
        swp[t] = acc;
        __syncthreads();
        const float* w4p = &swp[lane * 4];
        float wx = w4p[0], wy = w4p[1], wz = w4p[2], ww = w4p[3];
        int base = bid * 64 + wid * 16;
        #pragma unroll 1
        for (int rb = 0; rb < 4; ++rb) {
            float4 v[4];
            #pragma unroll
            for (int k = 0; k < 4; ++k)
                v[k] = ((const float4*)(x + (size_t)(base + rb * 4 + k) * 256))[lane];
            #pragma unroll
            for (int k = 0; k < 4; ++k) {
                int row = base + rb * 4 + k;
                ushort4 o;
                o.x = f2bf(v[k].x); o.y = f2bf(v[k].y); o.z = f2bf(v[k].z); o.w = f2bf(v[k].w);
                ((ushort4*)(XB + (size_t)row * 256))[lane] = o;
                float a = fmaf(v[k].x, wx, fmaf(v[k].y, wy, fmaf(v[k].z, wz, v[k].w * ww)));
                for (int off = 32; off > 0; off >>= 1) a += __shfl_down(a, off, 64);
                if (lane == 0) Z[row] = a;
            }
        }
    } else {
        __shared__ float sT[64][65];
        int bt = bid - 256;
        int tr = (bt >> 2) * 64, tc = (bt & 3) * 64;
        #pragma unroll
        for (int p = 0; p < 4; ++p) {
            int r = p * 16 + (t >> 4), c = (t & 15) * 4;
            float4 w = *(const float4*)&W[(size_t)(tr + r) * 256 + tc + c];
            sT[r][c] = w.x; sT[r][c + 1] = w.y; sT[r][c + 2] = w.z; sT[r][c + 3] = w.w;
        }
        __syncthreads();
        #pragma unroll
        for (int p = 0; p < 2; ++p) {
            int nl = p * 32 + (t >> 3), kl = (t & 7) * 8;
            u16 tmp[8];
            #pragma unroll
            for (int j = 0; j < 8; ++j) tmp[j] = f2bf(sT[kl + j][nl]);
            *(int4*)&WT[(size_t)(tc + nl) * 256 + tr + kl] = *(const int4*)tmp;
        }
    }
}

// =============== k2: XWBT = (XB@WT^T)^T per batch (blocks 0-255) | adj->AB bf16 + y (blocks 256-1279) ===============
__global__ __launch_bounds__(256) void k2(const u16* __restrict__ XB,
                                          const u16* __restrict__ WT,
                                          const float* __restrict__ adj,
                                          const float* __restrict__ Z,
                                          u16* __restrict__ XWBT,
                                          u16* __restrict__ AB,
                                          float* __restrict__ Y) {
    int t = threadIdx.x, lane = t & 63, wid = t >> 6;
    if (blockIdx.x < 256) {
        __shared__ short sA[128][72];
        __shared__ short sB[128][72];
        int bm = blockIdx.x >> 1, bn = blockIdx.x & 1;
        int wr = (wid >> 1) * 64, wc = (wid & 1) * 64;
        int fm = lane & 15, fq = lane >> 4;

        f32x4 acc[4][4];
        #pragma unroll
        for (int i = 0; i < 4; ++i)
            #pragma unroll
            for (int j = 0; j < 4; ++j)
                acc[i][j] = (f32x4){0.f, 0.f, 0.f, 0.f};

        int sr = t >> 1, half = (t & 1) * 32;
        const u16* gA = XB + ((size_t)(bm * 128 + sr)) * 256 + half;
        const u16* gB = WT + ((size_t)(bn * 128 + sr)) * 256 + half;

        for (int kt = 0; kt < 4; ++kt) {
            __syncthreads();
            #pragma unroll
            for (int q = 0; q < 4; ++q) {
                *(int4*)&sA[sr][half + q * 8] = *(const int4*)&gA[kt * 64 + q * 8];
                *(int4*)&sB[sr][half + q * 8] = *(const int4*)&gB[kt * 64 + q * 8];
            }
            __syncthreads();
            #pragma unroll
            for (int ks = 0; ks < 64; ks += 32) {
                bf16x8 af[4], bfv[4];
                #pragma unroll
                for (int i = 0; i < 4; ++i)
                    af[i] = *(const bf16x8*)&sA[wr + i * 16 + fm][ks + fq * 8];
                #pragma unroll
                for (int j = 0; j < 4; ++j)
                    bfv[j] = *(const bf16x8*)&sB[wc + j * 16 + fm][ks + fq * 8];
                #pragma unroll
                for (int i = 0; i < 4; ++i)
                    #pragma unroll
                    for (int j = 0; j < 4; ++j)
                        acc[i][j] = __builtin_amdgcn_mfma_f32_16x16x32_bf16(af[i], bfv[j], acc[i][j], 0, 0, 0);
            }
        }
        // write transposed: XWBT[b][n][m_local], m contiguous
        int b = bm >> 3;
        #pragma unroll
        for (int i = 0; i < 4; ++i) {
            int rloc = (bm & 7) * 128 + wr + i * 16 + fq * 4;
            #pragma unroll
            for (int j = 0; j < 4; ++j) {
                int c = bn * 128 + wc + j * 16 + fm;
                u16 tmp[4];
                #pragma unroll
                for (int r = 0; r < 4; ++r) tmp[r] = f2bf(acc[i][j][r]);
                *(unsigned long long*)&XWBT[(size_t)b * 262144 + (size_t)c * 1024 + rloc] =
                    *(const unsigned long long*)tmp;
            }
        }
    } else {
        int g = blockIdx.x - 256;
        int b = g >> 6, grp = g & 63;
        __shared__ float sZ[1024];
        ((float4*)sZ)[t] = ((const float4*)(Z + (b << 10)))[t];
        __syncthreads();
        const float* z0 = &sZ[lane * 4];
        #pragma unroll 1
        for (int rr = 0; rr < 4; ++rr) {
            int row = (b << 10) + grp * 16 + wid * 4 + rr;
            const float4* ar = (const float4*)(adj + (size_t)row * 1024);
            float4 v0 = ar[lane], v1 = ar[64 + lane], v2 = ar[128 + lane], v3 = ar[192 + lane];
            u16* abr = AB + (size_t)row * 1024;
            ushort4 o0, o1, o2, o3;
            o0.x = f2bf(v0.x); o0.y = f2bf(v0.y); o0.z = f2bf(v0.z); o0.w = f2bf(v0.w);
            o1.x = f2bf(v1.x); o1.y = f2bf(v1.y); o1.z = f2bf(v1.z); o1.w = f2bf(v1.w);
            o2.x = f2bf(v2.x); o2.y = f2bf(v2.y); o2.z = f2bf(v2.z); o2.w = f2bf(v2.w);
            o3.x = f2bf(v3.x); o3.y = f2bf(v3.y); o3.z = f2bf(v3.z); o3.w = f2bf(v3.w);
            ((ushort4*)abr)[lane] = o0;
            ((ushort4*)abr)[64 + lane] = o1;
            ((ushort4*)abr)[128 + lane] = o2;
            ((ushort4*)abr)[192 + lane] = o3;
            float a = v0.x * z0[0] + v0.y * z0[1] + v0.z * z0[2] + v0.w * z0[3];
            a += v1.x * z0[256] + v1.y * z0[257] + v1.z * z0[258] + v1.w * z0[259];
            a += v2.x * z0[512] + v2.y * z0[513] + v2.z * z0[514] + v2.w * z0[515];
            a += v3.x * z0[768] + v3.y * z0[769] + v3.z * z0[770] + v3.w * z0[771];
            for (int off = 32; off > 0; off >>= 1) a += __shfl_down(a, off, 64);
            if (lane == 0) Y[row] = a;
        }
    }
}

// =============== k3: per-batch stable ascending argsort + mask pooling ===============
__device__ inline u64 shfl_xor_u64(u64 v, int m) {
    int lo = __shfl_xor((int)(v & 0xffffffffULL), m, 64);
    int hi = __shfl_xor((int)(v >> 32), m, 64);
    return ((u64)(unsigned)hi << 32) | (unsigned)lo;
}

__global__ __launch_bounds__(1024) void k3(const float* __restrict__ Y,
                                           const int* __restrict__ maskIn,
                                           const int* __restrict__ nNodes,
                                           const float* __restrict__ bias,
                                           const float* __restrict__ pool,
                                           float* __restrict__ SCALE,
                                           float* __restrict__ NM,
                                           float* __restrict__ newN,
                                           u64* __restrict__ NMBITS) {
    __shared__ u64 s[1024];
    __shared__ int wsum[16];
    __shared__ int nmLoc[1024];
    __shared__ float redb[4], redq[4];
    __shared__ float sBP, sINV;

    int b = blockIdx.x, t = threadIdx.x, lane = t & 63, wid = t >> 6;
    int base = b << 10;

    if (t < 256) {
        float pv = pool[t];
        float bv = bias[t] * pv;
        float qv = pv * pv;
        for (int off = 32; off > 0; off >>= 1) {
            bv += __shfl_down(bv, off, 64);
            qv += __shfl_down(qv, off, 64);
        }
        if (lane == 0) { redb[wid] = bv; redq[wid] = qv; }
    }
    __syncthreads();
    if (t == 0) {
        sBP  = redb[0] + redb[1] + redb[2] + redb[3];
        sINV = 1.0f / sqrtf(redq[0] + redq[1] + redq[2] + redq[3]);
    }

    float ky = Y[base + t];
    unsigned u = __float_as_uint(ky);
    u = (u & 0x80000000u) ? ~u : (u | 0x80000000u);
    u64 val = ((u64)u << 32) | (unsigned)t;

    for (int k = 2; k <= 1024; k <<= 1) {
        bool up = ((t & k) == 0);
        int j = k >> 1;
        for (; j >= 64; j >>= 1) {
            s[t] = val; __syncthreads();
            u64 p = s[t ^ j]; __syncthreads();
            bool keepMin = (up == ((t & j) == 0));
            bool pLess = p < val;
            val = (keepMin == pLess) ? p : val;
        }
        for (; j >= 1; j >>= 1) {
            u64 p = shfl_xor_u64(val, j);
            bool keepMin = (up == ((t & j) == 0));
            bool pLess = p < val;
            val = (keepMin == pLess) ? p : val;
        }
    }

    int idx = (int)(val & 1023u);
    int mval = maskIn[base + idx];
    int sc = mval;
    for (int off = 1; off < 64; off <<= 1) {
        int nv = __shfl_up(sc, off, 64);
        if (lane >= off) sc += nv;
    }
    if (lane == 63) wsum[wid] = sc;
    __syncthreads();
    int offset = 0;
    for (int w = 0; w < wid; ++w) offset += wsum[w];
    int rank = sc + offset - mval;
    int nn = nNodes[b];
    int nrem = (int)((float)nn * 0.5f);
    int nm = (mval == 1 && rank < nrem) ? 0 : mval;
    nmLoc[idx] = nm;
    NM[base + idx] = (float)nm;
    if (t == 0) newN[b] = (float)(nn - nrem);
    __syncthreads();

    int myNm = nmLoc[t];
    u64 bmask = __ballot(myNm != 0);
    if (lane == 0) NMBITS[b * 16 + wid] = bmask;
    float yr = Y[base + t];
    SCALE[base + t] = myNm ? tanhf((yr + sBP) * sINV) : 0.0f;
}

// =============== k4: H=AB@XWBT^T + x_out epilogue (blocks 0-255) | AO dense write (blocks 256-1279) ===============
__global__ __launch_bounds__(256) void k4(const u16* __restrict__ AB,
                                          const u16* __restrict__ XWBT,
                                          const float* __restrict__ SCALE,
                                          const float* __restrict__ bias,
                                          const u64* __restrict__ NMBITS,
                                          float* __restrict__ XO,
                                          float* __restrict__ AO) {
    int t = threadIdx.x, lane = t & 63, wid = t >> 6;
    if (blockIdx.x < 256) {
        __shared__ short sA[128][72];
        __shared__ short sB[128][72];
        int idx = blockIdx.x;
        int bn = idx & 1, bmt = (idx >> 1) & 7, b = idx >> 4;
        int wr = (wid >> 1) * 64, wc = (wid & 1) * 64;
        int fm = lane & 15, fq = lane >> 4;

        f32x4 acc[4][4];
        #pragma unroll
        for (int i = 0; i < 4; ++i)
            #pragma unroll
            for (int j = 0; j < 4; ++j)
                acc[i][j] = (f32x4){0.f, 0.f, 0.f, 0.f};

        int sr = t >> 1, half = (t & 1) * 32;
        const u16* gA = AB + ((size_t)(b * 1024 + bmt * 128 + sr)) * 1024 + half;
        const u16* gB = XWBT + (size_t)b * 262144 + (size_t)(bn * 128 + sr) * 1024 + half;

        for (int kt = 0; kt < 16; ++kt) {
            __syncthreads();
            #pragma unroll
            for (int q = 0; q < 4; ++q) {
                *(int4*)&sA[sr][half + q * 8] = *(const int4*)&gA[kt * 64 + q * 8];
                *(int4*)&sB[sr][half + q * 8] = *(const int4*)&gB[kt * 64 + q * 8];
            }
            __syncthreads();
            #pragma unroll
            for (int ks = 0; ks < 64; ks += 32) {
                bf16x8 af[4], bfv[4];
                #pragma unroll
                for (int i = 0; i < 4; ++i)
                    af[i] = *(const bf16x8*)&sA[wr + i * 16 + fm][ks + fq * 8];
                #pragma unroll
                for (int j = 0; j < 4; ++j)
                    bfv[j] = *(const bf16x8*)&sB[wc + j * 16 + fm][ks + fq * 8];
                #pragma unroll
                for (int i = 0; i < 4; ++i)
                    #pragma unroll
                    for (int j = 0; j < 4; ++j)
                        acc[i][j] = __builtin_amdgcn_mfma_f32_16x16x32_bf16(af[i], bfv[j], acc[i][j], 0, 0, 0);
            }
        }
        float bj[4];
        #pragma unroll
        for (int j = 0; j < 4; ++j) bj[j] = bias[bn * 128 + wc + j * 16 + fm];
        int mb = (b << 10) + bmt * 128 + wr;
        #pragma unroll
        for (int i = 0; i < 4; ++i) {
            int m0 = mb + i * 16 + fq * 4;
            float s0 = SCALE[m0], s1 = SCALE[m0 + 1], s2 = SCALE[m0 + 2], s3 = SCALE[m0 + 3];
            #pragma unroll
            for (int j = 0; j < 4; ++j) {
                int c = bn * 128 + wc + j * 16 + fm;
                float* xo = XO + (size_t)m0 * 256 + c;
                xo[0]   = (acc[i][j][0] + bj[j]) * s0;
                xo[256] = (acc[i][j][1] + bj[j]) * s1;
                xo[512] = (acc[i][j][2] + bj[j]) * s2;
                xo[768] = (acc[i][j][3] + bj[j]) * s3;
            }
        }
    } else {
        int g = blockIdx.x - 256;
        int b = g >> 6, grp = g & 63;
        __shared__ u64 sBits[16];
        if (t < 16) sBits[t] = NMBITS[b * 16 + t];
        __syncthreads();
        int c0 = t * 4;
        u64 wb = sBits[c0 >> 6] >> (c0 & 63);
        float m0 = (wb & 1) ? 1.f : 0.f;
        float m1 = ((wb >> 1) & 1) ? 1.f : 0.f;
        float m2 = ((wb >> 2) & 1) ? 1.f : 0.f;
        float m3 = ((wb >> 3) & 1) ? 1.f : 0.f;
        #pragma unroll 1
        for (int r = 0; r < 16; ++r) {
            int rloc = grp * 16 + r;
            int nmRow = (int)((sBits[rloc >> 6] >> (rloc & 63)) & 1ULL);
            float4* aor = (float4*)(AO + (size_t)((b << 10) + rloc) * 1024);
            if (nmRow) {
                ushort4 ab = ((const ushort4*)(AB + (size_t)((b << 10) + rloc) * 1024))[t];
                float4 o;
                o.x = ab.x ? m0 : 0.f;
                o.y = ab.y ? m1 : 0.f;
                o.z = ab.z ? m2 : 0.f;
                o.w = ab.w ? m3 : 0.f;
                aor[t] = o;
            } else {
                aor[t] = make_float4(0.f, 0.f, 0.f, 0.f);
            }
        }
    }
}

extern "C" void kernel_launch(void* const* d_in, const int* in_sizes, int n_in,
                              void* d_out, int out_size, void* d_ws, size_t ws_size,
                              hipStream_t stream) {
    const float* x      = (const float*)d_in[0];
    const float* adj    = (const float*)d_in[1];
    const int*   mask   = (const int*)d_in[2];
    const int*   nnodes = (const int*)d_in[3];
    const float* W      = (const float*)d_in[4];
    const float* bias   = (const float*)d_in[5];
    const float* pool   = (const float*)d_in[6];

    float* out = (float*)d_out;
    float* XO  = out;
    float* AO  = out + ADJ_OFF;
    float* NM  = out + MASK_OFF;
    float* NNo = out + NN_OFF;

    char* w = (char*)d_ws;
    u16*   XB     = (u16*)(w);                    //  8,388,608 B
    u16*   WT     = (u16*)(w + 8388608);          //    131,072
    u16*   XWBT   = (u16*)(w + 8519680);          //  8,388,608
    u16*   AB     = (u16*)(w + 16908288);         // 33,554,432
    float* Z      = (float*)(w + 50462720);       //     65,536
    float* Y      = (float*)(w + 50528256);       //     65,536
    float* SCALE  = (float*)(w + 50593792);       //     65,536
    u64*   NMBITS = (u64*)(w + 50659328);         //      2,048

    k1<<<272, 256, 0, stream>>>(x, W, pool, XB, WT, Z);
    k2<<<1280, 256, 0, stream>>>(XB, WT, adj, Z, XWBT, AB, Y);
    k3<<<Bsz, 1024, 0, stream>>>(Y, mask, nnodes, bias, pool, SCALE, NM, NNo, NMBITS);
    k4<<<1280, 256, 0, stream>>>(AB, XWBT, SCALE, bias, NMBITS, XO, AO);
}